// Round 2
// baseline (161.589 us; speedup 1.0000x reference)
//
#include <hip/hip_runtime.h>

#define B_ 64
#define S_ 512
#define H_ 768
#define L_ 9
#define TPB 16                       // tokens per block (4 waves x 4 tokens)
#define BPR (S_ / TPB)               // blocks per row = 32

// ---------------------------------------------------------------------------
// Fused kernel: per-row stream compaction (recomputed per block from the int32
// mask, 2KB/row, L2-resident) + gathered GEMV (768->9) + softmax. All f32.
// Block = 256 threads = 4 waves; each wave handles 4 output token slots;
// lane i owns h in [12i, 12i+12).
// ---------------------------------------------------------------------------
__global__ __launch_bounds__(256) void ner_kernel(const float* __restrict__ seq,
                                                  const int* __restrict__ mask,
                                                  const float* __restrict__ W,
                                                  const float* __restrict__ bias,
                                                  float* __restrict__ out) {
    __shared__ float wt[L_ * 3 * 64 * 4];   // 6912 floats: [(cls*3+j4)*64+lane] float4s
    __shared__ float bsh[L_];
    __shared__ int   srcrow[S_];            // output slot -> source token index
    __shared__ int   wsum[4];

    const int tid  = threadIdx.x;
    const int lane = tid & 63;
    const int w    = tid >> 6;
    const int row  = blockIdx.x / BPR;
    const int sub  = blockIdx.x % BPR;

    // ---- W -> LDS, lane-major float4 layout: wt[((cls*3+j4)*64+ln)*4+j] =
    //      W[(12*ln + 4*j4 + j)*9 + cls] ----
    for (int idx = tid; idx < L_ * 3 * 64 * 4; idx += 256) {
        int j    = idx & 3;
        int ln   = (idx >> 2) & 63;
        int rest = idx >> 8;               // cls*3 + j4
        int j4   = rest % 3;
        int cls  = rest / 3;
        wt[idx] = W[(12 * ln + 4 * j4 + j) * L_ + cls];
    }
    if (tid < L_) bsh[tid] = bias[tid];

    // ---- full-row compaction scan; thread t owns entries 2t, 2t+1 ----
    const int e0 = 2 * tid, e1 = 2 * tid + 1;
    const int v0 = (mask[row * S_ + e0] != 0);
    const int v1 = (mask[row * S_ + e1] != 0);
    const unsigned long long b0 = __ballot(v0);
    const unsigned long long b1 = __ballot(v1);
    const unsigned long long lt = (1ULL << lane) - 1ULL;
    const int pfx  = __popcll(b0 & lt) + __popcll(b1 & lt);  // valid entries before e0 in wave chunk
    const int wtot = __popcll(b0) + __popcll(b1);
    if (lane == 0) wsum[w] = wtot;
    __syncthreads();                        // wsum ready; wt/bsh writes also done

    int woff = 0;
#pragma unroll
    for (int i = 0; i < 4; i++)
        if (i < w) woff += wsum[i];
    const int cnt = wsum[0] + wsum[1] + wsum[2] + wsum[3];
    const int p0  = woff + pfx;
    if (v0) srcrow[p0] = e0;
    if (v1) srcrow[p0 + v0] = e1;
    __syncthreads();                        // srcrow ready (and wt visible)

    // ---- gather x for this wave's 4 token slots ----
    const int basep = sub * TPB + w * 4;    // first output slot (within row)
    float x[4][12];
#pragma unroll
    for (int t = 0; t < 4; t++) {
        const int pp = basep + t;
        if (pp < cnt) {                     // wave-uniform branch
            const int src = srcrow[pp];     // LDS broadcast
            const float4* p4 = reinterpret_cast<const float4*>(
                seq + ((size_t)row * S_ + src) * H_ + lane * 12);
            float4 a0 = p4[0], a1 = p4[1], a2 = p4[2];
            x[t][0] = a0.x; x[t][1] = a0.y; x[t][2]  = a0.z; x[t][3]  = a0.w;
            x[t][4] = a1.x; x[t][5] = a1.y; x[t][6]  = a1.z; x[t][7]  = a1.w;
            x[t][8] = a2.x; x[t][9] = a2.y; x[t][10] = a2.z; x[t][11] = a2.w;
        } else {
#pragma unroll
            for (int k = 0; k < 12; k++) x[t][k] = 0.0f;
        }
    }

    // ---- per-lane partial dot products ----
    float acc[4][L_];
#pragma unroll
    for (int t = 0; t < 4; t++)
#pragma unroll
        for (int c = 0; c < L_; c++) acc[t][c] = 0.0f;

    const float4* wt4 = reinterpret_cast<const float4*>(wt);
#pragma unroll
    for (int cls = 0; cls < L_; cls++) {
#pragma unroll
        for (int j4 = 0; j4 < 3; j4++) {
            float4 wv = wt4[(cls * 3 + j4) * 64 + lane];
#pragma unroll
            for (int t = 0; t < 4; t++) {
                acc[t][cls] += x[t][j4 * 4 + 0] * wv.x + x[t][j4 * 4 + 1] * wv.y
                             + x[t][j4 * 4 + 2] * wv.z + x[t][j4 * 4 + 3] * wv.w;
            }
        }
    }

    // ---- 64-lane butterfly: every lane ends with full sums ----
#pragma unroll
    for (int t = 0; t < 4; t++) {
#pragma unroll
        for (int c = 0; c < L_; c++) {
            float v = acc[t][c];
            v += __shfl_xor(v, 1);
            v += __shfl_xor(v, 2);
            v += __shfl_xor(v, 4);
            v += __shfl_xor(v, 8);
            v += __shfl_xor(v, 16);
            v += __shfl_xor(v, 32);
            acc[t][c] = v;
        }
    }

    // ---- softmax epilogue: lane = t*9 + c for t in [0,4), c in [0,9) ----
    if (lane < 36) {
#pragma unroll
        for (int t = 0; t < 4; t++) {
            if (lane >= t * 9 && lane < t * 9 + 9) {
                const int c = lane - t * 9;
                float lg[L_];
                float m = -3.4e38f;
#pragma unroll
                for (int c2 = 0; c2 < L_; c2++) {
                    lg[c2] = acc[t][c2] + bsh[c2];
                    m = fmaxf(m, lg[c2]);
                }
                float s = 0.0f, mine = 0.0f;
#pragma unroll
                for (int c2 = 0; c2 < L_; c2++) {
                    float e = __expf(lg[c2] - m);
                    s += e;
                    if (c2 == c) mine = e;
                }
                out[((size_t)row * S_ + basep) * L_ + lane] = mine / s;
            }
        }
    }
}

extern "C" void kernel_launch(void* const* d_in, const int* in_sizes, int n_in,
                              void* d_out, int out_size, void* d_ws, size_t ws_size,
                              hipStream_t stream) {
    const float* seq  = (const float*)d_in[0];   // [64,512,768] f32
    const int*   mask = (const int*)d_in[1];     // [64,512] int32
    const float* W    = (const float*)d_in[2];   // [768,9] f32
    const float* bias = (const float*)d_in[3];   // [9] f32
    float*       out  = (float*)d_out;           // [64,512,9] f32

    ner_kernel<<<B_ * BPR, 256, 0, stream>>>(seq, mask, W, bias, out);
}

// Round 3
// 154.784 us; speedup vs baseline: 1.0440x; 1.0440x over previous
//
#include <hip/hip_runtime.h>

#define B_ 64
#define S_ 512
#define H_ 768
#define L_ 9
#define TPB 32                       // tokens per block
#define BPR (S_ / TPB)               // 16 blocks per row
#define NPASS 2                      // 4-token passes per wave (4 waves x 8 tokens)

// ---------------------------------------------------------------------------
// Fused: per-row compaction (from int32 mask, LDS) + gathered GEMV (768->9)
// + softmax. f32 in/out. Block = 256 threads = 4 waves; each wave handles 8
// token slots as 2 passes of 4; lane i owns h in [12i,12i+12).
// Reduction: reduce-scatter padded to 16 classes (17 shuffles/token), then
// group-parallel softmax (group g of 16 lanes finishes token g of the pass).
// ---------------------------------------------------------------------------
__global__ __launch_bounds__(256) void ner_kernel(const float* __restrict__ seq,
                                                  const int* __restrict__ mask,
                                                  const float* __restrict__ W,
                                                  const float* __restrict__ bias,
                                                  float* __restrict__ out) {
    __shared__ float wt[L_ * 3 * 64 * 4];   // [(cls*3+j4)*64+lane] float4s
    __shared__ float bsh[16];
    __shared__ int   srcrow[S_];
    __shared__ int   wsum[4];

    const int tid  = threadIdx.x;
    const int lane = tid & 63;
    const int w    = tid >> 6;
    const int row  = blockIdx.x / BPR;
    const int sub  = blockIdx.x % BPR;

    // ---- W -> LDS (coalesced global reads, transposed scatter into LDS) ----
    // wt[((c*3+j4)*64+ln)*4+j] = W[h*9+c], h = 12*ln+4*j4+j
    for (int idx = tid; idx < H_ * L_; idx += 256) {
        float val = W[idx];
        int h  = idx / 9;
        int c  = idx - 9 * h;
        int ln = h / 12;
        int r  = h - 12 * ln;
        wt[((c * 3 + (r >> 2)) * 64 + ln) * 4 + (r & 3)] = val;
    }
    if (tid < 16) bsh[tid] = (tid < L_) ? bias[tid] : 0.0f;

    // ---- full-row compaction scan; thread t owns mask entries 2t, 2t+1 ----
    const int e0 = 2 * tid, e1 = 2 * tid + 1;
    const int v0 = (mask[row * S_ + e0] != 0);
    const int v1 = (mask[row * S_ + e1] != 0);
    const unsigned long long b0 = __ballot(v0);
    const unsigned long long b1 = __ballot(v1);
    const unsigned long long lt = (1ULL << lane) - 1ULL;
    const int pfx  = __popcll(b0 & lt) + __popcll(b1 & lt);
    const int wtot = __popcll(b0) + __popcll(b1);
    if (lane == 0) wsum[w] = wtot;
    __syncthreads();

    int woff = 0;
#pragma unroll
    for (int i = 0; i < 4; i++)
        if (i < w) woff += wsum[i];
    const int cnt = wsum[0] + wsum[1] + wsum[2] + wsum[3];
    const int p0  = woff + pfx;
    if (v0) srcrow[p0] = e0;
    if (v1) srcrow[p0 + v0] = e1;
    __syncthreads();                        // srcrow + wt + bsh ready

    // class owned by this lane after reduce-scatter = bit-reverse4(lane&15)
    const int cls = ((lane & 1) << 3) | (((lane >> 1) & 1) << 2)
                  | (((lane >> 2) & 1) << 1) | ((lane >> 3) & 1);
    const float bb = bsh[cls];
    const int g = lane >> 4;                // epilogue group -> token-in-pass

    const float4* wt4 = reinterpret_cast<const float4*>(wt);

    for (int pass = 0; pass < NPASS; pass++) {
        const int basep = sub * TPB + w * (4 * NPASS) + pass * 4;

        // ---- gather x for 4 token slots ----
        float x[4][12];
#pragma unroll
        for (int t = 0; t < 4; t++) {
            const int pp = basep + t;
            if (pp < cnt) {                 // wave-uniform
                const int src = srcrow[pp];
                const float4* p4 = reinterpret_cast<const float4*>(
                    seq + ((size_t)row * S_ + src) * H_ + lane * 12);
                float4 a0 = p4[0], a1 = p4[1], a2 = p4[2];
                x[t][0] = a0.x; x[t][1] = a0.y; x[t][2]  = a0.z; x[t][3]  = a0.w;
                x[t][4] = a1.x; x[t][5] = a1.y; x[t][6]  = a1.z; x[t][7]  = a1.w;
                x[t][8] = a2.x; x[t][9] = a2.y; x[t][10] = a2.z; x[t][11] = a2.w;
            } else {
#pragma unroll
                for (int k = 0; k < 12; k++) x[t][k] = 0.0f;
            }
        }

        // ---- per-lane partial dot products ----
        float acc[4][L_];
#pragma unroll
        for (int t = 0; t < 4; t++)
#pragma unroll
            for (int c = 0; c < L_; c++) acc[t][c] = 0.0f;

#pragma unroll
        for (int c = 0; c < L_; c++) {
#pragma unroll
            for (int j4 = 0; j4 < 3; j4++) {
                float4 wv = wt4[(c * 3 + j4) * 64 + lane];
#pragma unroll
                for (int t = 0; t < 4; t++) {
                    acc[t][c] += x[t][j4 * 4 + 0] * wv.x + x[t][j4 * 4 + 1] * wv.y
                               + x[t][j4 * 4 + 2] * wv.z + x[t][j4 * 4 + 3] * wv.w;
                }
            }
        }

        // ---- reduce-scatter over 64 lanes, classes padded to 16 ----
        float logit[4];
#pragma unroll
        for (int t = 0; t < 4; t++) {
            float v[16];
#pragma unroll
            for (int c = 0; c < L_; c++) v[c] = acc[t][c];
#pragma unroll
            for (int c = L_; c < 16; c++) v[c] = 0.0f;

            {   // xor 1: keep low 8 if bit0==0 else high 8
                const bool b = (lane & 1);
#pragma unroll
                for (int i = 0; i < 8; i++) {
                    float give = b ? v[i] : v[i + 8];
                    float got  = __shfl_xor(give, 1);
                    v[i] = (b ? v[i + 8] : v[i]) + got;
                }
            }
            {   // xor 2
                const bool b = ((lane >> 1) & 1);
#pragma unroll
                for (int i = 0; i < 4; i++) {
                    float give = b ? v[i] : v[i + 4];
                    float got  = __shfl_xor(give, 2);
                    v[i] = (b ? v[i + 4] : v[i]) + got;
                }
            }
            {   // xor 4
                const bool b = ((lane >> 2) & 1);
#pragma unroll
                for (int i = 0; i < 2; i++) {
                    float give = b ? v[i] : v[i + 2];
                    float got  = __shfl_xor(give, 4);
                    v[i] = (b ? v[i + 2] : v[i]) + got;
                }
            }
            {   // xor 8
                const bool b = ((lane >> 3) & 1);
                float give = b ? v[0] : v[1];
                float got  = __shfl_xor(give, 8);
                v[0] = (b ? v[1] : v[0]) + got;
            }
            v[0] += __shfl_xor(v[0], 16);
            v[0] += __shfl_xor(v[0], 32);
            logit[t] = v[0];                // full sum for class `cls`, all lanes
        }

        // ---- group-parallel softmax: group g handles token (basep+g) ----
        float lg = (g == 0) ? logit[0] : (g == 1) ? logit[1]
                 : (g == 2) ? logit[2] : logit[3];
        lg += bb;
        float lx = (cls < L_) ? lg : -1e30f;
        float m = lx;
        m = fmaxf(m, __shfl_xor(m, 1));
        m = fmaxf(m, __shfl_xor(m, 2));
        m = fmaxf(m, __shfl_xor(m, 4));
        m = fmaxf(m, __shfl_xor(m, 8));
        float e = (cls < L_) ? __expf(lx - m) : 0.0f;
        float ssum = e;
        ssum += __shfl_xor(ssum, 1);
        ssum += __shfl_xor(ssum, 2);
        ssum += __shfl_xor(ssum, 4);
        ssum += __shfl_xor(ssum, 8);
        if (cls < L_)
            out[((size_t)row * S_ + basep + g) * L_ + cls] = e / ssum;
    }
}

extern "C" void kernel_launch(void* const* d_in, const int* in_sizes, int n_in,
                              void* d_out, int out_size, void* d_ws, size_t ws_size,
                              hipStream_t stream) {
    const float* seq  = (const float*)d_in[0];   // [64,512,768] f32
    const int*   mask = (const int*)d_in[1];     // [64,512] int32
    const float* W    = (const float*)d_in[2];   // [768,9] f32
    const float* bias = (const float*)d_in[3];   // [9] f32
    float*       out  = (float*)d_out;           // [64,512,9] f32

    ner_kernel<<<B_ * BPR, 256, 0, stream>>>(seq, mask, W, bias, out);
}

// Round 4
// 148.862 us; speedup vs baseline: 1.0855x; 1.0398x over previous
//
#include <hip/hip_runtime.h>

#define B_ 64
#define S_ 512
#define H_ 768
#define L_ 9
#define TPB 32                       // tokens per block
#define BPR (S_ / TPB)               // 16 blocks per row
#define NPASS 2                      // 4-token passes per wave (4 waves x 8 tokens)

// ---------------------------------------------------------------------------
// Fused: per-row compaction (from int32 mask, LDS) + gathered GEMV (768->9)
// + softmax. f32 in/out. Block = 256 threads = 4 waves; each wave handles 8
// token slots as 2 passes of 4; lane i owns h in [12i,12i+12).
// Invalid slots (>= cnt) produce the CONSTANT vector softmax(bias): blocks
// entirely past cnt skip W-preload/gather/GEMV and just store constants;
// mixed blocks early-out per 4-token pass.
// ---------------------------------------------------------------------------
__global__ __launch_bounds__(256) void ner_kernel(const float* __restrict__ seq,
                                                  const int* __restrict__ mask,
                                                  const float* __restrict__ W,
                                                  const float* __restrict__ bias,
                                                  float* __restrict__ out) {
    __shared__ float wt[L_ * 3 * 64 * 4];   // [(cls*3+j4)*64+lane] float4s
    __shared__ float bsh[16];
    __shared__ int   srcrow[S_];
    __shared__ int   wsum[4];

    const int tid  = threadIdx.x;
    const int lane = tid & 63;
    const int w    = tid >> 6;
    const int row  = blockIdx.x / BPR;
    const int sub  = blockIdx.x % BPR;

    // ---- constant probs for invalid slots: softmax(bias), per-thread scalar ----
    float cprob[L_];
    {
        float m = -3.4e38f;
#pragma unroll
        for (int c = 0; c < L_; c++) { cprob[c] = bias[c]; m = fmaxf(m, cprob[c]); }
        float s = 0.0f;
#pragma unroll
        for (int c = 0; c < L_; c++) { cprob[c] = __expf(cprob[c] - m); s += cprob[c]; }
        const float inv = 1.0f / s;
#pragma unroll
        for (int c = 0; c < L_; c++) cprob[c] *= inv;
    }

    // ---- full-row compaction scan; thread t owns mask entries 2t, 2t+1 ----
    const int e0 = 2 * tid, e1 = 2 * tid + 1;
    const int v0 = (mask[row * S_ + e0] != 0);
    const int v1 = (mask[row * S_ + e1] != 0);
    const unsigned long long b0 = __ballot(v0);
    const unsigned long long b1 = __ballot(v1);
    const unsigned long long lt = (1ULL << lane) - 1ULL;
    const int pfx  = __popcll(b0 & lt) + __popcll(b1 & lt);
    const int wtot = __popcll(b0) + __popcll(b1);
    if (lane == 0) wsum[w] = wtot;
    __syncthreads();

    const int cnt = wsum[0] + wsum[1] + wsum[2] + wsum[3];

    // ---- whole-block early-out: every slot in this block is invalid ----
    if (sub * TPB >= cnt) {                 // block-uniform
        const int base = (row * S_ + sub * TPB) * L_;
        for (int idx = tid; idx < TPB * L_; idx += 256)
            out[base + idx] = cprob[idx % L_];
        return;
    }

    // ---- scatter compaction map into LDS ----
    int woff = 0;
#pragma unroll
    for (int i = 0; i < 4; i++)
        if (i < w) woff += wsum[i];
    const int p0 = woff + pfx;
    if (v0) srcrow[p0] = e0;
    if (v1) srcrow[p0 + v0] = e1;

    // ---- W -> LDS (coalesced global reads, transposed scatter into LDS) ----
    // wt[((c*3+j4)*64+ln)*4+j] = W[h*9+c], h = 12*ln+4*j4+j
    for (int idx = tid; idx < H_ * L_; idx += 256) {
        float val = W[idx];
        int h  = idx / 9;
        int c  = idx - 9 * h;
        int ln = h / 12;
        int r  = h - 12 * ln;
        wt[((c * 3 + (r >> 2)) * 64 + ln) * 4 + (r & 3)] = val;
    }
    if (tid < 16) bsh[tid] = (tid < L_) ? bias[tid] : 0.0f;
    __syncthreads();                        // srcrow + wt + bsh ready

    // class owned by this lane after reduce-scatter = bit-reverse4(lane&15)
    const int cls = ((lane & 1) << 3) | (((lane >> 1) & 1) << 2)
                  | (((lane >> 2) & 1) << 1) | ((lane >> 3) & 1);
    const float bb = bsh[cls];
    const int g = lane >> 4;                // epilogue group -> token-in-pass

    const float4* wt4 = reinterpret_cast<const float4*>(wt);

    for (int pass = 0; pass < NPASS; pass++) {
        const int basep = sub * TPB + w * (4 * NPASS) + pass * 4;

        // ---- per-pass early-out: all 4 slots invalid -> constant probs ----
        if (basep >= cnt) {                 // wave-uniform
            if (lane < 36)
                out[((size_t)row * S_ + basep) * L_ + lane] = cprob[lane % L_];
            continue;
        }

        // ---- gather x for 4 token slots ----
        float x[4][12];
#pragma unroll
        for (int t = 0; t < 4; t++) {
            const int pp = basep + t;
            if (pp < cnt) {                 // wave-uniform
                const int src = srcrow[pp];
                const float4* p4 = reinterpret_cast<const float4*>(
                    seq + ((size_t)row * S_ + src) * H_ + lane * 12);
                float4 a0 = p4[0], a1 = p4[1], a2 = p4[2];
                x[t][0] = a0.x; x[t][1] = a0.y; x[t][2]  = a0.z; x[t][3]  = a0.w;
                x[t][4] = a1.x; x[t][5] = a1.y; x[t][6]  = a1.z; x[t][7]  = a1.w;
                x[t][8] = a2.x; x[t][9] = a2.y; x[t][10] = a2.z; x[t][11] = a2.w;
            } else {
#pragma unroll
                for (int k = 0; k < 12; k++) x[t][k] = 0.0f;
            }
        }

        // ---- per-lane partial dot products ----
        float acc[4][L_];
#pragma unroll
        for (int t = 0; t < 4; t++)
#pragma unroll
            for (int c = 0; c < L_; c++) acc[t][c] = 0.0f;

#pragma unroll
        for (int c = 0; c < L_; c++) {
#pragma unroll
            for (int j4 = 0; j4 < 3; j4++) {
                float4 wv = wt4[(c * 3 + j4) * 64 + lane];
#pragma unroll
                for (int t = 0; t < 4; t++) {
                    acc[t][c] += x[t][j4 * 4 + 0] * wv.x + x[t][j4 * 4 + 1] * wv.y
                               + x[t][j4 * 4 + 2] * wv.z + x[t][j4 * 4 + 3] * wv.w;
                }
            }
        }

        // ---- reduce-scatter over 64 lanes, classes padded to 16 ----
        float logit[4];
#pragma unroll
        for (int t = 0; t < 4; t++) {
            float v[16];
#pragma unroll
            for (int c = 0; c < L_; c++) v[c] = acc[t][c];
#pragma unroll
            for (int c = L_; c < 16; c++) v[c] = 0.0f;

            {   // xor 1: keep low 8 if bit0==0 else high 8
                const bool b = (lane & 1);
#pragma unroll
                for (int i = 0; i < 8; i++) {
                    float give = b ? v[i] : v[i + 8];
                    float got  = __shfl_xor(give, 1);
                    v[i] = (b ? v[i + 8] : v[i]) + got;
                }
            }
            {   // xor 2
                const bool b = ((lane >> 1) & 1);
#pragma unroll
                for (int i = 0; i < 4; i++) {
                    float give = b ? v[i] : v[i + 4];
                    float got  = __shfl_xor(give, 2);
                    v[i] = (b ? v[i + 4] : v[i]) + got;
                }
            }
            {   // xor 4
                const bool b = ((lane >> 2) & 1);
#pragma unroll
                for (int i = 0; i < 2; i++) {
                    float give = b ? v[i] : v[i + 2];
                    float got  = __shfl_xor(give, 4);
                    v[i] = (b ? v[i + 2] : v[i]) + got;
                }
            }
            {   // xor 8
                const bool b = ((lane >> 3) & 1);
                float give = b ? v[0] : v[1];
                float got  = __shfl_xor(give, 8);
                v[0] = (b ? v[1] : v[0]) + got;
            }
            v[0] += __shfl_xor(v[0], 16);
            v[0] += __shfl_xor(v[0], 32);
            logit[t] = v[0];                // full sum for class `cls`, all lanes
        }

        // ---- group-parallel softmax: group g handles token (basep+g) ----
        float lg = (g == 0) ? logit[0] : (g == 1) ? logit[1]
                 : (g == 2) ? logit[2] : logit[3];
        lg += bb;
        float lx = (cls < L_) ? lg : -1e30f;
        float m = lx;
        m = fmaxf(m, __shfl_xor(m, 1));
        m = fmaxf(m, __shfl_xor(m, 2));
        m = fmaxf(m, __shfl_xor(m, 4));
        m = fmaxf(m, __shfl_xor(m, 8));
        float e = (cls < L_) ? __expf(lx - m) : 0.0f;
        float ssum = e;
        ssum += __shfl_xor(ssum, 1);
        ssum += __shfl_xor(ssum, 2);
        ssum += __shfl_xor(ssum, 4);
        ssum += __shfl_xor(ssum, 8);
        if (cls < L_)
            out[((size_t)row * S_ + basep + g) * L_ + cls] = e / ssum;
    }
}

extern "C" void kernel_launch(void* const* d_in, const int* in_sizes, int n_in,
                              void* d_out, int out_size, void* d_ws, size_t ws_size,
                              hipStream_t stream) {
    const float* seq  = (const float*)d_in[0];   // [64,512,768] f32
    const int*   mask = (const int*)d_in[1];     // [64,512] int32
    const float* W    = (const float*)d_in[2];   // [768,9] f32
    const float* bias = (const float*)d_in[3];   // [9] f32
    float*       out  = (float*)d_out;           // [64,512,9] f32

    ner_kernel<<<B_ * BPR, 256, 0, stream>>>(seq, mask, W, bias, out);
}